// Round 2
// baseline (764.464 us; speedup 1.0000x reference)
//
#include <hip/hip_runtime.h>
#include <hip/hip_bf16.h>
#include <math.h>

// Problem constants: B=16, S=256 -> N=4096 tokens; D=256; U=2000 urls (f32).
#define N_TOK 4096
#define DIM   256
#define NURL  2000
#define KMAX  8     // tokens processed per matrix stream
#define UNR   8     // rows of trans in flight per wave (8 x 1KB)

// One block (1 wave, 64 lanes) per URL. Block u:
//  1) ballot-scan urls[] (16 KB, L1-resident) to collect its token indices
//  2) stream trans[u] ONCE per <=KMAX-token chunk, accumulating KMAX matvecs
//     simultaneously: lane l owns output columns 4l..4l+3 (float4 loads,
//     64 lanes x 16B = 1KB/row coalesced); x values broadcast from LDS.
// URLs with zero tokens exit without fetching trans -> HBM traffic ~= unique
// urls (~1742) * 256KB ~= 446 MB instead of 4096 * 256KB = 1.07 GB.
__global__ __launch_bounds__(64) void source_bias_seq_kernel(
    const float* __restrict__ inp,    // [N, D]
    const int*   __restrict__ urls,   // [N]
    const float* __restrict__ trans,  // [U, D, D]
    const float* __restrict__ bias,   // [U, D]
    float*       __restrict__ out)    // [N, D]
{
    const int u    = blockIdx.x;
    const int lane = threadIdx.x;  // 0..63

    __shared__ int   toks[KMAX];
    __shared__ float xs[KMAX * DIM];          // 8 KB
    float4* xs4 = reinterpret_cast<float4*>(xs);

    const float4* T4 = reinterpret_cast<const float4*>(
                           trans + (size_t)u * DIM * DIM);

    float4 bv;
    bool bias_loaded = false;

    int done = 0;  // tokens of this url already processed
    for (;;) {
        // ---- scan pass: collect the next up-to-KMAX tokens with url == u ----
        int running = 0;  // matches seen so far in this pass (uniform)
        for (int base = 0; base < N_TOK; base += 64) {
            const int idx   = base + lane;
            const bool match = (urls[idx] == u);
            const unsigned long long m = __ballot(match);
            if (match) {
                const int rank = running + __popcll(m & ((1ull << lane) - 1ull));
                const int slot = rank - done;
                if (slot >= 0 && slot < KMAX) toks[slot] = idx;
            }
            running += __popcll(m);
            if (running >= done + KMAX) break;  // uniform branch
        }
        const int k = min(running - done, KMAX);
        if (k <= 0) break;  // no (more) tokens for this url
        __syncthreads();

        if (!bias_loaded) {
            bv = reinterpret_cast<const float4*>(bias + (size_t)u * DIM)[lane];
            bias_loaded = true;
        }

        // ---- stage x vectors for this chunk (zero-pad j >= k) ----
        #pragma unroll
        for (int j = 0; j < KMAX; ++j) {
            float4 v = make_float4(0.f, 0.f, 0.f, 0.f);
            if (j < k) {
                const int tj = toks[j];
                v = reinterpret_cast<const float4*>(inp + (size_t)tj * DIM)[lane];
            }
            xs4[j * (DIM / 4) + lane] = v;
        }
        __syncthreads();

        float4 acc[KMAX];
        #pragma unroll
        for (int j = 0; j < KMAX; ++j) acc[j] = bv;

        // ---- stream the matrix: UNR rows in flight, KMAX matvecs at once ----
        for (int d0 = 0; d0 < DIM; d0 += UNR) {
            float4 tv[UNR];
            #pragma unroll
            for (int i = 0; i < UNR; ++i)
                tv[i] = T4[(size_t)(d0 + i) * (DIM / 4) + lane];

            #pragma unroll
            for (int j = 0; j < KMAX; ++j) {
                // broadcast reads (all lanes same address): 2 x b128 per j
                const float4 xa = xs4[j * (DIM / 4) + (d0 >> 2)];
                const float4 xb = xs4[j * (DIM / 4) + (d0 >> 2) + 1];
                const float xj[UNR] = {xa.x, xa.y, xa.z, xa.w,
                                       xb.x, xb.y, xb.z, xb.w};
                #pragma unroll
                for (int i = 0; i < UNR; ++i) {
                    acc[j].x = fmaf(xj[i], tv[i].x, acc[j].x);
                    acc[j].y = fmaf(xj[i], tv[i].y, acc[j].y);
                    acc[j].z = fmaf(xj[i], tv[i].z, acc[j].z);
                    acc[j].w = fmaf(xj[i], tv[i].w, acc[j].w);
                }
            }
        }

        // ---- epilogue: tanh + store (only real tokens) ----
        #pragma unroll
        for (int j = 0; j < KMAX; ++j) {
            if (j < k) {
                const int tj = toks[j];
                float4 o;
                o.x = tanhf(acc[j].x);
                o.y = tanhf(acc[j].y);
                o.z = tanhf(acc[j].z);
                o.w = tanhf(acc[j].w);
                reinterpret_cast<float4*>(out + (size_t)tj * DIM)[lane] = o;
            }
        }

        done += k;
        __syncthreads();  // protect toks/xs before next pass overwrites
    }
}

extern "C" void kernel_launch(void* const* d_in, const int* in_sizes, int n_in,
                              void* d_out, int out_size, void* d_ws, size_t ws_size,
                              hipStream_t stream) {
    const float* inp   = (const float*)d_in[0];  // [B,S,D] f32
    const int*   urls  = (const int*)  d_in[1];  // [B,S]   i32
    const float* trans = (const float*)d_in[2];  // [U,D,D] f32
    const float* bias  = (const float*)d_in[3];  // [U,D]   f32
    float*       out   = (float*)d_out;

    source_bias_seq_kernel<<<NURL, 64, 0, stream>>>(inp, urls, trans, bias, out);
}